// Round 6
// baseline (625.506 us; speedup 1.0000x reference)
//
#include <hip/hip_runtime.h>
#include <hip/hip_bf16.h>
#include <math.h>

#define NN 50000
#define EE 800000
#define ET 850000
#define NB 196          // ceil(NN/256)
#define NEG 0.2f

static __device__ __forceinline__ float lrelu(float x){ return x > 0.f ? x : NEG * x; }
static __device__ __forceinline__ void edge_sd(const int* __restrict__ ei, int e, int& s, int& d){
  if (e < EE){ s = ei[e]; d = ei[e + EE]; } else { s = e - EE; d = s; }
}
static __device__ __forceinline__ float dot4(float4 a, float4 b, float acc){
  acc = fmaf(a.x, b.x, acc); acc = fmaf(a.y, b.y, acc);
  acc = fmaf(a.z, b.z, acc); acc = fmaf(a.w, b.w, acc);
  return acc;
}

// ---- CSR build ----
__global__ __launch_bounds__(256) void k_hist(const int* __restrict__ ei, int* __restrict__ deg_i)
{
  int e = blockIdx.x * 256 + threadIdx.x;
  if (e >= ET) return;
  int s, d; edge_sd(ei, e, s, d);
  atomicAdd(deg_i + d, 1);
}

__global__ __launch_bounds__(256) void k_scan_part(const int* __restrict__ deg_i, int* __restrict__ bsum)
{
  __shared__ int wsum[4];
  int t = threadIdx.x;
  int i = blockIdx.x * 256 + t;
  int v = (i < NN) ? deg_i[i] : 0;
  int r = v;
#pragma unroll
  for (int off = 32; off; off >>= 1) r += __shfl_xor(r, off);
  if ((t & 63) == 0) wsum[t >> 6] = r;
  __syncthreads();
  if (t == 0) bsum[blockIdx.x] = wsum[0] + wsum[1] + wsum[2] + wsum[3];
}

__global__ __launch_bounds__(256) void k_scan_top(const int* __restrict__ bsum, int* __restrict__ boff)
{
  __shared__ int bs[256];
  int t = threadIdx.x;
  int v = (t < NB) ? bsum[t] : 0;
  bs[t] = v;
  __syncthreads();
  for (int off = 1; off < 256; off <<= 1){
    int add = (t >= off) ? bs[t - off] : 0;
    __syncthreads();
    bs[t] += add;
    __syncthreads();
  }
  if (t < NB) boff[t] = bs[t] - v;
}

__global__ __launch_bounds__(256) void k_scan_fin(const int* __restrict__ deg_i,
    const int* __restrict__ boff, int* __restrict__ row_start, float* __restrict__ dinv)
{
  __shared__ int bs[256];
  int t = threadIdx.x;
  int i = blockIdx.x * 256 + t;
  int v = (i < NN) ? deg_i[i] : 0;
  bs[t] = v;
  __syncthreads();
  for (int off = 1; off < 256; off <<= 1){
    int add = (t >= off) ? bs[t - off] : 0;
    __syncthreads();
    bs[t] += add;
    __syncthreads();
  }
  if (i < NN){
    row_start[i] = boff[blockIdx.x] + bs[t] - v;
    dinv[i] = rsqrtf(fmaxf((float)v, 1.0f));
  }
  if (i == 0) row_start[NN] = ET;
}

__global__ __launch_bounds__(256) void k_fill(const int* __restrict__ ei,
    const int* __restrict__ row_start, int* __restrict__ cur, int* __restrict__ csr)
{
  int e = blockIdx.x * 256 + threadIdx.x;
  if (e >= ET) return;
  int s, d; edge_sd(ei, e, s, d);
  int pos = atomicAdd(cur + d, 1);
  csr[row_start[d] + pos] = s;
}

// ---- tiny: w2as = W2 @ a_src2, w2ad = W2 @ a_dst2 (48 each) ----
__global__ __launch_bounds__(64) void k_w2(const float* __restrict__ W2,
    const float* __restrict__ as2, const float* __restrict__ ad2,
    float* __restrict__ w2as, float* __restrict__ w2ad)
{
  int k = threadIdx.x;
  if (k >= 48) return;
  float s = 0.f, d = 0.f;
  for (int j = 0; j < 128; ++j){
    float w = W2[(size_t)k * 128 + j];
    s = fmaf(w, as2[j], s);
    d = fmaf(w, ad2[j], d);
  }
  w2as[k] = s; w2ad[k] = d;
}

// ---- GAT1 GEMM: h1 = x @ W1 (512->48) + fused es1/ed1 ----
// A kept [node][k] (aligned b128), B transposed [out][k]; k-unroll 4
__global__ __launch_bounds__(256) void k_gat1_gemm(
    const float* __restrict__ x, const float* __restrict__ W1,
    const float* __restrict__ as1, const float* __restrict__ ad1,
    float* __restrict__ h1, float* __restrict__ es1, float* __restrict__ ed1)
{
  __shared__ float Xs[64][68];    // [node][k]  (68*4 % 16 == 0, banks 4n+k)
  __shared__ float Bt[48][68];    // [out][k]   transposed W1
  int t = threadIdx.x;
  int tx = t & 15, ty = t >> 4;
  int n0 = blockIdx.x * 64;
  float acc[4][3] = {};
  for (int kt = 0; kt < 512; kt += 64){
    __syncthreads();
    // stage x tile (64 nodes x 64 k) directly (no transpose)
#pragma unroll
    for (int p = 0; p < 4; ++p){
      int f = t + p * 256;
      int node = f >> 4, kq = f & 15;
      float4 v = make_float4(0.f, 0.f, 0.f, 0.f);
      int gn = n0 + node;
      if (gn < NN) v = *(const float4*)(x + (size_t)gn * 512 + kt + kq * 4);
      *(float4*)&Xs[node][kq * 4] = v;
    }
    // stage W1 rows kt..kt+63 transposed into Bt[out][k]
#pragma unroll
    for (int p = 0; p < 3; ++p){
      int f = t + p * 256;
      int k = f / 12, oq = f % 12;
      float4 v = *(const float4*)(W1 + (size_t)(kt + k) * 48 + oq * 4);
      Bt[oq * 4 + 0][k] = v.x; Bt[oq * 4 + 1][k] = v.y;
      Bt[oq * 4 + 2][k] = v.z; Bt[oq * 4 + 3][k] = v.w;
    }
    __syncthreads();
#pragma unroll 4
    for (int k4 = 0; k4 < 64; k4 += 4){
      float4 a0 = *(const float4*)&Xs[ty * 4 + 0][k4];
      float4 a1 = *(const float4*)&Xs[ty * 4 + 1][k4];
      float4 a2 = *(const float4*)&Xs[ty * 4 + 2][k4];
      float4 a3 = *(const float4*)&Xs[ty * 4 + 3][k4];
      float4 b0 = *(const float4*)&Bt[tx * 3 + 0][k4];
      float4 b1 = *(const float4*)&Bt[tx * 3 + 1][k4];
      float4 b2 = *(const float4*)&Bt[tx * 3 + 2][k4];
      acc[0][0] = dot4(a0, b0, acc[0][0]); acc[0][1] = dot4(a0, b1, acc[0][1]); acc[0][2] = dot4(a0, b2, acc[0][2]);
      acc[1][0] = dot4(a1, b0, acc[1][0]); acc[1][1] = dot4(a1, b1, acc[1][1]); acc[1][2] = dot4(a1, b2, acc[1][2]);
      acc[2][0] = dot4(a2, b0, acc[2][0]); acc[2][1] = dot4(a2, b1, acc[2][1]); acc[2][2] = dot4(a2, b2, acc[2][2]);
      acc[3][0] = dot4(a3, b0, acc[3][0]); acc[3][1] = dot4(a3, b1, acc[3][1]); acc[3][2] = dot4(a3, b2, acc[3][2]);
    }
  }
#pragma unroll
  for (int i = 0; i < 4; ++i){
    int gn = n0 + ty * 4 + i;
    float ps0 = 0.f, ps1 = 0.f, ps2 = 0.f, pd0 = 0.f, pd1 = 0.f, pd2 = 0.f;
#pragma unroll
    for (int j = 0; j < 3; ++j){
      int o = tx * 3 + j;
      int h = o >> 4;
      float a = acc[i][j];
      float vs = a * as1[o], vd = a * ad1[o];
      if (h == 0){ ps0 += vs; pd0 += vd; }
      else if (h == 1){ ps1 += vs; pd1 += vd; }
      else { ps2 += vs; pd2 += vd; }
    }
#pragma unroll
    for (int off = 1; off < 16; off <<= 1){
      ps0 += __shfl_xor(ps0, off, 16); ps1 += __shfl_xor(ps1, off, 16); ps2 += __shfl_xor(ps2, off, 16);
      pd0 += __shfl_xor(pd0, off, 16); pd1 += __shfl_xor(pd1, off, 16); pd2 += __shfl_xor(pd2, off, 16);
    }
    if (gn < NN){
      float* o = h1 + (size_t)gn * 48 + tx * 3;
      o[0] = acc[i][0]; o[1] = acc[i][1]; o[2] = acc[i][2];
      if (tx == 0){
        es1[(size_t)gn * 3 + 0] = ps0; es1[(size_t)gn * 3 + 1] = ps1; es1[(size_t)gn * 3 + 2] = ps2;
        ed1[(size_t)gn * 3 + 0] = pd0; ed1[(size_t)gn * 3 + 1] = pd1; ed1[(size_t)gn * 3 + 2] = pd2;
      }
    }
  }
}

// ---- GAT1 aggregate: wave/node, online softmax, fused +b1+ELU, fused es2/ed2 ----
__global__ __launch_bounds__(256) void k_gat1_agg(
    const int* __restrict__ csr, const int* __restrict__ row_start,
    const float* __restrict__ es1, const float* __restrict__ ed1,
    const float* __restrict__ h1, const float* __restrict__ b1,
    const float* __restrict__ w2as, const float* __restrict__ w2ad,
    float* __restrict__ o1, float* __restrict__ es2, float* __restrict__ ed2)
{
  int dn = (blockIdx.x * 256 + threadIdx.x) >> 6;
  int lane = threadIdx.x & 63;
  if (dn >= NN) return;
  bool act = lane < 48;
  int hd = act ? (lane >> 4) : 0;
  int beg = row_start[dn], end = row_start[dn + 1];
  float edv = ed1[(size_t)dn * 3 + hd];
  float m = -INFINITY, sum = 0.f, acc = 0.f;
  int i = beg;
  for (; i + 1 < end; i += 2){
    int s0 = csr[i], s1 = csr[i + 1];
    float e0 = lrelu(es1[(size_t)s0 * 3 + hd] + edv);
    float e1 = lrelu(es1[(size_t)s1 * 3 + hd] + edv);
    float h0 = act ? h1[(size_t)s0 * 48 + lane] : 0.f;
    float h1v = act ? h1[(size_t)s1 * 48 + lane] : 0.f;
    float mn = fmaxf(m, fmaxf(e0, e1));
    float sc = __expf(m - mn), w0 = __expf(e0 - mn), w1 = __expf(e1 - mn);
    sum = sum * sc + w0 + w1;
    acc = acc * sc + h0 * w0 + h1v * w1;
    m = mn;
  }
  if (i < end){
    int s0 = csr[i];
    float e0 = lrelu(es1[(size_t)s0 * 3 + hd] + edv);
    float h0 = act ? h1[(size_t)s0 * 48 + lane] : 0.f;
    float mn = fmaxf(m, e0);
    float sc = __expf(m - mn), w0 = __expf(e0 - mn);
    sum = sum * sc + w0;
    acc = acc * sc + h0 * w0;
  }
  float v = 0.f;
  if (act){
    v = acc / sum + b1[lane];
    v = v > 0.f ? v : expm1f(v);
    o1[(size_t)dn * 48 + lane] = v;
  }
  // fused GAT2 attention scalars: es2 = o1[dn]·w2as, ed2 = o1[dn]·w2ad
  float ps = act ? v * w2as[lane] : 0.f;
  float pd = act ? v * w2ad[lane] : 0.f;
#pragma unroll
  for (int off = 32; off; off >>= 1){ ps += __shfl_xor(ps, off); pd += __shfl_xor(pd, off); }
  if (lane == 0){ es2[dn] = ps; ed2[dn] = pd; }
}

// ---- GAT2 aggregate over 48-dim o1 (linearized): agg2[d] = softmax-weighted sum ----
__global__ __launch_bounds__(256) void k_gat2_agg(
    const int* __restrict__ csr, const int* __restrict__ row_start,
    const float* __restrict__ es2, const float* __restrict__ ed2,
    const float* __restrict__ o1, float* __restrict__ agg2)
{
  int dn = (blockIdx.x * 256 + threadIdx.x) >> 6;
  int lane = threadIdx.x & 63;
  if (dn >= NN) return;
  bool act = lane < 48;
  int beg = row_start[dn], end = row_start[dn + 1];
  float edv = ed2[dn];
  float m = -INFINITY, sum = 0.f, acc = 0.f;
  int i = beg;
  for (; i + 1 < end; i += 2){
    int s0 = csr[i], s1 = csr[i + 1];
    float e0 = lrelu(es2[s0] + edv);
    float e1 = lrelu(es2[s1] + edv);
    float h0 = act ? o1[(size_t)s0 * 48 + lane] : 0.f;
    float h1v = act ? o1[(size_t)s1 * 48 + lane] : 0.f;
    float mn = fmaxf(m, fmaxf(e0, e1));
    float sc = __expf(m - mn), w0 = __expf(e0 - mn), w1 = __expf(e1 - mn);
    sum = sum * sc + w0 + w1;
    acc = acc * sc + h0 * w0 + h1v * w1;
    m = mn;
  }
  if (i < end){
    int s0 = csr[i];
    float e0 = lrelu(es2[s0] + edv);
    float h0 = act ? o1[(size_t)s0 * 48 + lane] : 0.f;
    float mn = fmaxf(m, e0);
    float sc = __expf(m - mn), w0 = __expf(e0 - mn);
    sum = sum * sc + w0;
    acc = acc * sc + h0 * w0;
  }
  if (act) agg2[(size_t)dn * 48 + lane] = acc / sum;
}

// ---- GAT2 post: o2 = log_softmax(agg2 @ W2 + b2) ----
__global__ __launch_bounds__(256) void k_gat2_post(const float* __restrict__ agg2,
    const float* __restrict__ W2, const float* __restrict__ b2, float* __restrict__ o2)
{
  __shared__ float As[64][52];     // [node][k]
  __shared__ float Bt[128][52];    // [out][k] transposed W2
  int t = threadIdx.x, tx = t & 15, ty = t >> 4;
  int n0 = blockIdx.x * 64;
#pragma unroll
  for (int p = 0; p < 3; ++p){
    int f = t + p * 256;            // 768 float4 = 64 nodes x 12
    int node = f / 12, kq = f % 12;
    float4 v = make_float4(0.f, 0.f, 0.f, 0.f);
    if (n0 + node < NN) v = *(const float4*)(agg2 + (size_t)(n0 + node) * 48 + kq * 4);
    *(float4*)&As[node][kq * 4] = v;
  }
#pragma unroll
  for (int p = 0; p < 6; ++p){
    int f = t + p * 256;            // 1536 float4 = 48 rows x 32
    int k = f >> 5, cq = f & 31;
    float4 v = *(const float4*)(W2 + (size_t)k * 128 + cq * 4);
    Bt[cq * 4 + 0][k] = v.x; Bt[cq * 4 + 1][k] = v.y;
    Bt[cq * 4 + 2][k] = v.z; Bt[cq * 4 + 3][k] = v.w;
  }
  __syncthreads();
  float acc[4][8] = {};
#pragma unroll 3
  for (int k4 = 0; k4 < 48; k4 += 4){
    float4 a[4], b[8];
#pragma unroll
    for (int i = 0; i < 4; ++i) a[i] = *(const float4*)&As[ty * 4 + i][k4];
#pragma unroll
    for (int j = 0; j < 4; ++j){
      b[j]     = *(const float4*)&Bt[tx * 4 + j][k4];
      b[4 + j] = *(const float4*)&Bt[64 + tx * 4 + j][k4];
    }
#pragma unroll
    for (int i = 0; i < 4; ++i)
#pragma unroll
      for (int j = 0; j < 8; ++j)
        acc[i][j] = dot4(a[i], b[j], acc[i][j]);
  }
  // epilogue: +b2, row log_softmax (row split over 16 tx lanes), store
  float bb[8];
#pragma unroll
  for (int j = 0; j < 4; ++j){ bb[j] = b2[tx * 4 + j]; bb[4 + j] = b2[64 + tx * 4 + j]; }
#pragma unroll
  for (int i = 0; i < 4; ++i){
    int gn = n0 + ty * 4 + i;
    float v[8];
#pragma unroll
    for (int j = 0; j < 8; ++j) v[j] = acc[i][j] + bb[j];
    float mx = v[0];
#pragma unroll
    for (int j = 1; j < 8; ++j) mx = fmaxf(mx, v[j]);
#pragma unroll
    for (int off = 1; off < 16; off <<= 1) mx = fmaxf(mx, __shfl_xor(mx, off, 16));
    float es = 0.f;
#pragma unroll
    for (int j = 0; j < 8; ++j) es += __expf(v[j] - mx);
#pragma unroll
    for (int off = 1; off < 16; off <<= 1) es += __shfl_xor(es, off, 16);
    float lse = mx + __logf(es);
    if (gn < NN){
      float4 o0 = make_float4(v[0] - lse, v[1] - lse, v[2] - lse, v[3] - lse);
      float4 o1v = make_float4(v[4] - lse, v[5] - lse, v[6] - lse, v[7] - lse);
      *(float4*)(o2 + (size_t)gn * 128 + tx * 4) = o0;
      *(float4*)(o2 + (size_t)gn * 128 + tx * 4 + 64) = o1v;
    }
  }
}

// ---- GCN aggregate of o2 with dinv weights: aggD[d] = dinv[d]*Σ dinv[s]*o2[s] ----
__global__ __launch_bounds__(256) void k_gcn_agg(
    const int* __restrict__ csr, const int* __restrict__ row_start,
    const float* __restrict__ dinv, const float* __restrict__ o2,
    float* __restrict__ aggD)
{
  int wid = (blockIdx.x * 256 + threadIdx.x) >> 6;
  int lane = threadIdx.x & 63;
  int half = lane >> 5, l32 = lane & 31;
  int d = wid * 2 + half;
  if (d >= NN) return;
  int beg = row_start[d], end = row_start[d + 1];
  float ax = 0.f, ay = 0.f, az = 0.f, aw = 0.f;
  float bx = 0.f, by = 0.f, bz = 0.f, bw = 0.f;
  int i = beg;
  for (; i + 1 < end; i += 2){
    int s0 = csr[i], s1 = csr[i + 1];
    float d0 = dinv[s0], d1 = dinv[s1];
    float4 v0 = *(const float4*)(o2 + (size_t)s0 * 128 + l32 * 4);
    float4 v1 = *(const float4*)(o2 + (size_t)s1 * 128 + l32 * 4);
    ax = fmaf(v0.x, d0, ax); ay = fmaf(v0.y, d0, ay); az = fmaf(v0.z, d0, az); aw = fmaf(v0.w, d0, aw);
    bx = fmaf(v1.x, d1, bx); by = fmaf(v1.y, d1, by); bz = fmaf(v1.z, d1, bz); bw = fmaf(v1.w, d1, bw);
  }
  if (i < end){
    int s0 = csr[i];
    float d0 = dinv[s0];
    float4 v0 = *(const float4*)(o2 + (size_t)s0 * 128 + l32 * 4);
    ax = fmaf(v0.x, d0, ax); ay = fmaf(v0.y, d0, ay); az = fmaf(v0.z, d0, az); aw = fmaf(v0.w, d0, aw);
  }
  float dd = dinv[d];
  float4 ov = make_float4((ax + bx) * dd, (ay + by) * dd, (az + bz) * dd, (aw + bw) * dd);
  *(float4*)(aggD + (size_t)d * 128 + l32 * 4) = ov;
}

// ---- final fused: out = relu(aggD @ Wg + bg) @ Wl + bl  (T kept in LDS) ----
__global__ __launch_bounds__(256) void k_final(const float* __restrict__ aggD,
    const float* __restrict__ Wg, const float* __restrict__ bg,
    const float* __restrict__ Wl, const float* __restrict__ bl,
    float* __restrict__ out)
{
  __shared__ float Ta[64][132];   // phase1: A = aggD rows; phase2: A = relu(T+bg)
  __shared__ float Bt[128][36];   // [out][k-chunk] transposed weight chunk
  int t = threadIdx.x, tx = t & 15, ty = t >> 4;
  int n0 = blockIdx.x * 64;
#pragma unroll
  for (int p = 0; p < 8; ++p){
    int f = t + p * 256;           // 2048 float4 = 64 nodes x 32
    int node = f >> 5, cq = f & 31;
    float4 v = make_float4(0.f, 0.f, 0.f, 0.f);
    if (n0 + node < NN) v = *(const float4*)(aggD + (size_t)(n0 + node) * 128 + cq * 4);
    *(float4*)&Ta[node][cq * 4] = v;
  }
  float accv[4][8];
  const float* Wcur = Wg;
  for (int ph = 0; ph < 2; ++ph){
#pragma unroll
    for (int i = 0; i < 4; ++i)
#pragma unroll
      for (int j = 0; j < 8; ++j) accv[i][j] = 0.f;
    for (int kt = 0; kt < 128; kt += 32){
      __syncthreads();
#pragma unroll
      for (int p = 0; p < 4; ++p){
        int f = t + p * 256;       // 1024 float4 = 32 k x 32 cq
        int k = f >> 5, cq = f & 31;
        float4 v = *(const float4*)(Wcur + (size_t)(kt + k) * 128 + cq * 4);
        Bt[cq * 4 + 0][k] = v.x; Bt[cq * 4 + 1][k] = v.y;
        Bt[cq * 4 + 2][k] = v.z; Bt[cq * 4 + 3][k] = v.w;
      }
      __syncthreads();
#pragma unroll 2
      for (int k4 = 0; k4 < 32; k4 += 4){
        float4 a[4], b[8];
#pragma unroll
        for (int i = 0; i < 4; ++i) a[i] = *(const float4*)&Ta[ty * 4 + i][kt + k4];
#pragma unroll
        for (int j = 0; j < 4; ++j){
          b[j]     = *(const float4*)&Bt[tx * 4 + j][k4];
          b[4 + j] = *(const float4*)&Bt[64 + tx * 4 + j][k4];
        }
#pragma unroll
        for (int i = 0; i < 4; ++i)
#pragma unroll
          for (int j = 0; j < 8; ++j)
            accv[i][j] = dot4(a[i], b[j], accv[i][j]);
      }
    }
    if (ph == 0){
      __syncthreads();
      // T = relu(acc + bg) back into Ta
#pragma unroll
      for (int i = 0; i < 4; ++i){
        int n = ty * 4 + i;
        float4 w0, w1;
        w0.x = fmaxf(accv[i][0] + bg[tx * 4 + 0], 0.f);
        w0.y = fmaxf(accv[i][1] + bg[tx * 4 + 1], 0.f);
        w0.z = fmaxf(accv[i][2] + bg[tx * 4 + 2], 0.f);
        w0.w = fmaxf(accv[i][3] + bg[tx * 4 + 3], 0.f);
        w1.x = fmaxf(accv[i][4] + bg[64 + tx * 4 + 0], 0.f);
        w1.y = fmaxf(accv[i][5] + bg[64 + tx * 4 + 1], 0.f);
        w1.z = fmaxf(accv[i][6] + bg[64 + tx * 4 + 2], 0.f);
        w1.w = fmaxf(accv[i][7] + bg[64 + tx * 4 + 3], 0.f);
        *(float4*)&Ta[n][tx * 4] = w0;
        *(float4*)&Ta[n][tx * 4 + 64] = w1;
      }
      Wcur = Wl;
    }
  }
#pragma unroll
  for (int i = 0; i < 4; ++i){
    int gn = n0 + ty * 4 + i;
    if (gn < NN){
      float4 o0, o1v;
      o0.x = accv[i][0] + bl[tx * 4 + 0];
      o0.y = accv[i][1] + bl[tx * 4 + 1];
      o0.z = accv[i][2] + bl[tx * 4 + 2];
      o0.w = accv[i][3] + bl[tx * 4 + 3];
      o1v.x = accv[i][4] + bl[64 + tx * 4 + 0];
      o1v.y = accv[i][5] + bl[64 + tx * 4 + 1];
      o1v.z = accv[i][6] + bl[64 + tx * 4 + 2];
      o1v.w = accv[i][7] + bl[64 + tx * 4 + 3];
      *(float4*)(out + (size_t)gn * 128 + tx * 4) = o0;
      *(float4*)(out + (size_t)gn * 128 + tx * 4 + 64) = o1v;
    }
  }
}

extern "C" void kernel_launch(void* const* d_in, const int* in_sizes, int n_in,
                              void* d_out, int out_size, void* d_ws, size_t ws_size,
                              hipStream_t stream)
{
  const float* x   = (const float*)d_in[0];
  const int*   ei  = (const int*)d_in[1];
  const float* W1  = (const float*)d_in[2];
  const float* as1 = (const float*)d_in[3];
  const float* ad1 = (const float*)d_in[4];
  const float* b1  = (const float*)d_in[5];
  const float* W2  = (const float*)d_in[6];
  const float* as2 = (const float*)d_in[7];
  const float* ad2 = (const float*)d_in[8];
  const float* b2  = (const float*)d_in[9];
  const float* Wg  = (const float*)d_in[10];
  const float* bg  = (const float*)d_in[11];
  const float* Wl  = (const float*)d_in[12];
  const float* bl  = (const float*)d_in[13];
  float* out = (float*)d_out;

  float* ws = (float*)d_ws;
  const size_t n = NN;
  float* h1   = ws;                 // 48N
  float* o1   = ws + 48 * n;        // 48N
  float* agg2 = ws + 96 * n;        // 48N
  float* o2   = ws + 144 * n;       // 128N
  float* aggD = ws + 272 * n;       // 128N
  float* es1  = ws + 400 * n;       // 3N
  float* ed1  = ws + 403 * n;       // 3N
  float* es2  = ws + 406 * n;       // N
  float* ed2  = ws + 407 * n;       // N
  float* dinv = ws + 408 * n;       // N
  float* w2as = ws + 409 * n;       // 64
  float* w2ad = ws + 409 * n + 64;  // 64
  int* ints   = (int*)(ws + 410 * n);
  int* deg_i     = ints;            // N (zeroed)
  int* cur       = ints + n;        // N (zeroed)
  int* row_start = ints + 2 * n;    // N+1
  int* csr       = ints + 3 * n + 1;// ET
  int* bsum      = ints + 3 * n + 1 + ET;      // NB
  int* boff      = ints + 3 * n + 1 + ET + NB; // NB

  hipMemsetAsync(deg_i, 0, 2 * n * sizeof(int), stream);

  const int egrid = (ET + 255) / 256;
  const int wgrid = (NN * 64) / 256;        // one wave per node
  const int hgrid = (NN / 2 * 64) / 256;    // two nodes per wave
  const int ggrid = (NN + 63) / 64;
  k_hist<<<egrid, 256, 0, stream>>>(ei, deg_i);
  k_scan_part<<<NB, 256, 0, stream>>>(deg_i, bsum);
  k_scan_top<<<1, 256, 0, stream>>>(bsum, boff);
  k_scan_fin<<<NB, 256, 0, stream>>>(deg_i, boff, row_start, dinv);
  k_fill<<<egrid, 256, 0, stream>>>(ei, row_start, cur, csr);
  k_w2<<<1, 64, 0, stream>>>(W2, as2, ad2, w2as, w2ad);
  k_gat1_gemm<<<ggrid, 256, 0, stream>>>(x, W1, as1, ad1, h1, es1, ed1);
  k_gat1_agg<<<wgrid, 256, 0, stream>>>(csr, row_start, es1, ed1, h1, b1, w2as, w2ad, o1, es2, ed2);
  k_gat2_agg<<<wgrid, 256, 0, stream>>>(csr, row_start, es2, ed2, o1, agg2);
  k_gat2_post<<<ggrid, 256, 0, stream>>>(agg2, W2, b2, o2);
  k_gcn_agg<<<hgrid, 256, 0, stream>>>(csr, row_start, dinv, o2, aggD);
  k_final<<<ggrid, 256, 0, stream>>>(aggD, Wg, bg, Wl, bl, out);
}

// Round 7
// 563.916 us; speedup vs baseline: 1.1092x; 1.1092x over previous
//
#include <hip/hip_runtime.h>
#include <hip/hip_bf16.h>
#include <math.h>

#define NN 50000
#define EE 800000
#define ET 850000
#define NB 196          // ceil(NN/256)
#define NEG 0.2f

static __device__ __forceinline__ float lrelu(float x){ return x > 0.f ? x : NEG * x; }
static __device__ __forceinline__ void edge_sd(const int* __restrict__ ei, int e, int& s, int& d){
  if (e < EE){ s = ei[e]; d = ei[e + EE]; } else { s = e - EE; d = s; }
}

// ---- CSR build ----
__global__ __launch_bounds__(256) void k_hist(const int* __restrict__ ei, int* __restrict__ deg_i)
{
  int e = blockIdx.x * 256 + threadIdx.x;
  if (e >= ET) return;
  int s, d; edge_sd(ei, e, s, d);
  atomicAdd(deg_i + d, 1);
}

__global__ __launch_bounds__(256) void k_scan_part(const int* __restrict__ deg_i, int* __restrict__ bsum)
{
  __shared__ int wsum[4];
  int t = threadIdx.x;
  int i = blockIdx.x * 256 + t;
  int v = (i < NN) ? deg_i[i] : 0;
  int r = v;
#pragma unroll
  for (int off = 32; off; off >>= 1) r += __shfl_xor(r, off);
  if ((t & 63) == 0) wsum[t >> 6] = r;
  __syncthreads();
  if (t == 0) bsum[blockIdx.x] = wsum[0] + wsum[1] + wsum[2] + wsum[3];
}

__global__ __launch_bounds__(256) void k_scan_top(const int* __restrict__ bsum, int* __restrict__ boff)
{
  __shared__ int bs[256];
  int t = threadIdx.x;
  int v = (t < NB) ? bsum[t] : 0;
  bs[t] = v;
  __syncthreads();
  for (int off = 1; off < 256; off <<= 1){
    int add = (t >= off) ? bs[t - off] : 0;
    __syncthreads();
    bs[t] += add;
    __syncthreads();
  }
  if (t < NB) boff[t] = bs[t] - v;
}

__global__ __launch_bounds__(256) void k_scan_fin(const int* __restrict__ deg_i,
    const int* __restrict__ boff, int* __restrict__ row_start, float* __restrict__ dinv)
{
  __shared__ int bs[256];
  int t = threadIdx.x;
  int i = blockIdx.x * 256 + t;
  int v = (i < NN) ? deg_i[i] : 0;
  bs[t] = v;
  __syncthreads();
  for (int off = 1; off < 256; off <<= 1){
    int add = (t >= off) ? bs[t - off] : 0;
    __syncthreads();
    bs[t] += add;
    __syncthreads();
  }
  if (i < NN){
    row_start[i] = boff[blockIdx.x] + bs[t] - v;
    dinv[i] = rsqrtf(fmaxf((float)v, 1.0f));
  }
  if (i == 0) row_start[NN] = ET;
}

__global__ __launch_bounds__(256) void k_fill(const int* __restrict__ ei,
    const int* __restrict__ row_start, int* __restrict__ cur, int* __restrict__ csr)
{
  int e = blockIdx.x * 256 + threadIdx.x;
  if (e >= ET) return;
  int s, d; edge_sd(ei, e, s, d);
  int pos = atomicAdd(cur + d, 1);
  csr[row_start[d] + pos] = s;
}

// ---- tiny: w2as = W2 @ a_src2, w2ad = W2 @ a_dst2 (48 each) ----
__global__ __launch_bounds__(64) void k_w2(const float* __restrict__ W2,
    const float* __restrict__ as2, const float* __restrict__ ad2,
    float* __restrict__ w2as, float* __restrict__ w2ad)
{
  int k = threadIdx.x;
  if (k >= 48) return;
  float s = 0.f, d = 0.f;
  for (int j = 0; j < 128; ++j){
    float w = W2[(size_t)k * 128 + j];
    s = fmaf(w, as2[j], s);
    d = fmaf(w, ad2[j], d);
  }
  w2as[k] = s; w2ad[k] = d;
}

// ---- GAT1 GEMM: h1 = x @ W1 (512->48) + fused es1/ed1 ----
// natural layouts: Xs[node][k] (float4 k-reads, 2-way max), Bs[k][out] (scalar reads,
// 16 distinct banks since stride 3 odd). Staging is contiguous copies -> conflict-free.
__global__ __launch_bounds__(256) void k_gat1_gemm(
    const float* __restrict__ x, const float* __restrict__ W1,
    const float* __restrict__ as1, const float* __restrict__ ad1,
    float* __restrict__ h1, float* __restrict__ es1, float* __restrict__ ed1)
{
  __shared__ float Xs[64][68];    // [node][k], row stride 68 (mult of 4, !mult of 8)
  __shared__ float Bs[64][52];    // [k][out], row stride 52
  int t = threadIdx.x;
  int tx = t & 15, ty = t >> 4;
  int n0 = blockIdx.x * 64;
  float acc[4][3] = {};
  for (int kt = 0; kt < 512; kt += 64){
    __syncthreads();
#pragma unroll
    for (int p = 0; p < 4; ++p){
      int f = t + p * 256;
      int node = f >> 4, kq = f & 15;
      float4 v = make_float4(0.f, 0.f, 0.f, 0.f);
      int gn = n0 + node;
      if (gn < NN) v = *(const float4*)(x + (size_t)gn * 512 + kt + kq * 4);
      *(float4*)&Xs[node][kq * 4] = v;
    }
#pragma unroll
    for (int p = 0; p < 3; ++p){
      int f = t + p * 256;
      int k = f / 12, oq = f % 12;
      *(float4*)&Bs[k][oq * 4] = *(const float4*)(W1 + (size_t)(kt + k) * 48 + oq * 4);
    }
    __syncthreads();
#pragma unroll 4
    for (int k4 = 0; k4 < 64; k4 += 4){
      float4 q0 = *(const float4*)&Xs[ty * 4 + 0][k4];
      float4 q1 = *(const float4*)&Xs[ty * 4 + 1][k4];
      float4 q2 = *(const float4*)&Xs[ty * 4 + 2][k4];
      float4 q3 = *(const float4*)&Xs[ty * 4 + 3][k4];
      float a0[4] = {q0.x, q0.y, q0.z, q0.w};
      float a1[4] = {q1.x, q1.y, q1.z, q1.w};
      float a2[4] = {q2.x, q2.y, q2.z, q2.w};
      float a3[4] = {q3.x, q3.y, q3.z, q3.w};
#pragma unroll
      for (int kk = 0; kk < 4; ++kk){
        float b0 = Bs[k4 + kk][tx * 3 + 0];
        float b1 = Bs[k4 + kk][tx * 3 + 1];
        float b2 = Bs[k4 + kk][tx * 3 + 2];
        acc[0][0] = fmaf(a0[kk], b0, acc[0][0]); acc[0][1] = fmaf(a0[kk], b1, acc[0][1]); acc[0][2] = fmaf(a0[kk], b2, acc[0][2]);
        acc[1][0] = fmaf(a1[kk], b0, acc[1][0]); acc[1][1] = fmaf(a1[kk], b1, acc[1][1]); acc[1][2] = fmaf(a1[kk], b2, acc[1][2]);
        acc[2][0] = fmaf(a2[kk], b0, acc[2][0]); acc[2][1] = fmaf(a2[kk], b1, acc[2][1]); acc[2][2] = fmaf(a2[kk], b2, acc[2][2]);
        acc[3][0] = fmaf(a3[kk], b0, acc[3][0]); acc[3][1] = fmaf(a3[kk], b1, acc[3][1]); acc[3][2] = fmaf(a3[kk], b2, acc[3][2]);
      }
    }
  }
#pragma unroll
  for (int i = 0; i < 4; ++i){
    int gn = n0 + ty * 4 + i;
    float ps0 = 0.f, ps1 = 0.f, ps2 = 0.f, pd0 = 0.f, pd1 = 0.f, pd2 = 0.f;
#pragma unroll
    for (int j = 0; j < 3; ++j){
      int o = tx * 3 + j;
      int h = o >> 4;
      float a = acc[i][j];
      float vs = a * as1[o], vd = a * ad1[o];
      if (h == 0){ ps0 += vs; pd0 += vd; }
      else if (h == 1){ ps1 += vs; pd1 += vd; }
      else { ps2 += vs; pd2 += vd; }
    }
#pragma unroll
    for (int off = 1; off < 16; off <<= 1){
      ps0 += __shfl_xor(ps0, off, 16); ps1 += __shfl_xor(ps1, off, 16); ps2 += __shfl_xor(ps2, off, 16);
      pd0 += __shfl_xor(pd0, off, 16); pd1 += __shfl_xor(pd1, off, 16); pd2 += __shfl_xor(pd2, off, 16);
    }
    if (gn < NN){
      float* o = h1 + (size_t)gn * 48 + tx * 3;
      o[0] = acc[i][0]; o[1] = acc[i][1]; o[2] = acc[i][2];
      if (tx == 0){
        es1[(size_t)gn * 3 + 0] = ps0; es1[(size_t)gn * 3 + 1] = ps1; es1[(size_t)gn * 3 + 2] = ps2;
        ed1[(size_t)gn * 3 + 0] = pd0; ed1[(size_t)gn * 3 + 1] = pd1; ed1[(size_t)gn * 3 + 2] = pd2;
      }
    }
  }
}

// ---- GAT1 aggregate: wave/node, online softmax, fused +b1+ELU, fused es2/ed2 ----
__global__ __launch_bounds__(256) void k_gat1_agg(
    const int* __restrict__ csr, const int* __restrict__ row_start,
    const float* __restrict__ es1, const float* __restrict__ ed1,
    const float* __restrict__ h1, const float* __restrict__ b1,
    const float* __restrict__ w2as, const float* __restrict__ w2ad,
    float* __restrict__ o1, float* __restrict__ es2, float* __restrict__ ed2)
{
  int dn = (blockIdx.x * 256 + threadIdx.x) >> 6;
  int lane = threadIdx.x & 63;
  if (dn >= NN) return;
  bool act = lane < 48;
  int hd = act ? (lane >> 4) : 0;
  int beg = row_start[dn], end = row_start[dn + 1];
  float edv = ed1[(size_t)dn * 3 + hd];
  float m = -INFINITY, sum = 0.f, acc = 0.f;
  int i = beg;
  for (; i + 1 < end; i += 2){
    int s0 = csr[i], s1 = csr[i + 1];
    float e0 = lrelu(es1[(size_t)s0 * 3 + hd] + edv);
    float e1 = lrelu(es1[(size_t)s1 * 3 + hd] + edv);
    float h0 = act ? h1[(size_t)s0 * 48 + lane] : 0.f;
    float h1v = act ? h1[(size_t)s1 * 48 + lane] : 0.f;
    float mn = fmaxf(m, fmaxf(e0, e1));
    float sc = __expf(m - mn), w0 = __expf(e0 - mn), w1 = __expf(e1 - mn);
    sum = sum * sc + w0 + w1;
    acc = acc * sc + h0 * w0 + h1v * w1;
    m = mn;
  }
  if (i < end){
    int s0 = csr[i];
    float e0 = lrelu(es1[(size_t)s0 * 3 + hd] + edv);
    float h0 = act ? h1[(size_t)s0 * 48 + lane] : 0.f;
    float mn = fmaxf(m, e0);
    float sc = __expf(m - mn), w0 = __expf(e0 - mn);
    sum = sum * sc + w0;
    acc = acc * sc + h0 * w0;
  }
  float v = 0.f;
  if (act){
    v = acc / sum + b1[lane];
    v = v > 0.f ? v : expm1f(v);
    o1[(size_t)dn * 48 + lane] = v;
  }
  float ps = act ? v * w2as[lane] : 0.f;
  float pd = act ? v * w2ad[lane] : 0.f;
#pragma unroll
  for (int off = 32; off; off >>= 1){ ps += __shfl_xor(ps, off); pd += __shfl_xor(pd, off); }
  if (lane == 0){ es2[dn] = ps; ed2[dn] = pd; }
}

// ---- GAT2 aggregate over 48-dim o1 (linearized) ----
__global__ __launch_bounds__(256) void k_gat2_agg(
    const int* __restrict__ csr, const int* __restrict__ row_start,
    const float* __restrict__ es2, const float* __restrict__ ed2,
    const float* __restrict__ o1, float* __restrict__ agg2)
{
  int dn = (blockIdx.x * 256 + threadIdx.x) >> 6;
  int lane = threadIdx.x & 63;
  if (dn >= NN) return;
  bool act = lane < 48;
  int beg = row_start[dn], end = row_start[dn + 1];
  float edv = ed2[dn];
  float m = -INFINITY, sum = 0.f, acc = 0.f;
  int i = beg;
  for (; i + 1 < end; i += 2){
    int s0 = csr[i], s1 = csr[i + 1];
    float e0 = lrelu(es2[s0] + edv);
    float e1 = lrelu(es2[s1] + edv);
    float h0 = act ? o1[(size_t)s0 * 48 + lane] : 0.f;
    float h1v = act ? o1[(size_t)s1 * 48 + lane] : 0.f;
    float mn = fmaxf(m, fmaxf(e0, e1));
    float sc = __expf(m - mn), w0 = __expf(e0 - mn), w1 = __expf(e1 - mn);
    sum = sum * sc + w0 + w1;
    acc = acc * sc + h0 * w0 + h1v * w1;
    m = mn;
  }
  if (i < end){
    int s0 = csr[i];
    float e0 = lrelu(es2[s0] + edv);
    float h0 = act ? o1[(size_t)s0 * 48 + lane] : 0.f;
    float mn = fmaxf(m, e0);
    float sc = __expf(m - mn), w0 = __expf(e0 - mn);
    sum = sum * sc + w0;
    acc = acc * sc + h0 * w0;
  }
  if (act) agg2[(size_t)dn * 48 + lane] = acc / sum;
}

// ---- GAT2 post: o2 = log_softmax(agg2 @ W2 + b2), natural layouts ----
__global__ __launch_bounds__(256) void k_gat2_post(const float* __restrict__ agg2,
    const float* __restrict__ W2, const float* __restrict__ b2, float* __restrict__ o2)
{
  __shared__ float As[64][52];     // [node][k]
  __shared__ float Ws[48][128];    // [k][out] natural
  int t = threadIdx.x, tx = t & 15, ty = t >> 4;
  int n0 = blockIdx.x * 64;
#pragma unroll
  for (int p = 0; p < 3; ++p){
    int f = t + p * 256;            // 768 float4 = 64 nodes x 12
    int node = f / 12, kq = f % 12;
    float4 v = make_float4(0.f, 0.f, 0.f, 0.f);
    if (n0 + node < NN) v = *(const float4*)(agg2 + (size_t)(n0 + node) * 48 + kq * 4);
    *(float4*)&As[node][kq * 4] = v;
  }
#pragma unroll
  for (int p = 0; p < 6; ++p){
    int f = t + p * 256;            // 1536 float4 = 48 rows x 32
    int k = f >> 5, cq = f & 31;
    *(float4*)&Ws[k][cq * 4] = *(const float4*)(W2 + (size_t)k * 128 + cq * 4);
  }
  __syncthreads();
  float acc[4][8] = {};
#pragma unroll 4
  for (int k = 0; k < 48; ++k){
    float a0 = As[ty * 4 + 0][k];
    float a1 = As[ty * 4 + 1][k];
    float a2 = As[ty * 4 + 2][k];
    float a3 = As[ty * 4 + 3][k];
    float4 c0 = *(const float4*)&Ws[k][tx * 4];
    float4 c1 = *(const float4*)&Ws[k][tx * 4 + 64];
    float bv[8] = {c0.x, c0.y, c0.z, c0.w, c1.x, c1.y, c1.z, c1.w};
#pragma unroll
    for (int j = 0; j < 8; ++j){
      acc[0][j] = fmaf(a0, bv[j], acc[0][j]);
      acc[1][j] = fmaf(a1, bv[j], acc[1][j]);
      acc[2][j] = fmaf(a2, bv[j], acc[2][j]);
      acc[3][j] = fmaf(a3, bv[j], acc[3][j]);
    }
  }
  float bb[8];
#pragma unroll
  for (int j = 0; j < 4; ++j){ bb[j] = b2[tx * 4 + j]; bb[4 + j] = b2[64 + tx * 4 + j]; }
#pragma unroll
  for (int i = 0; i < 4; ++i){
    int gn = n0 + ty * 4 + i;
    float v[8];
#pragma unroll
    for (int j = 0; j < 8; ++j) v[j] = acc[i][j] + bb[j];
    float mx = v[0];
#pragma unroll
    for (int j = 1; j < 8; ++j) mx = fmaxf(mx, v[j]);
#pragma unroll
    for (int off = 1; off < 16; off <<= 1) mx = fmaxf(mx, __shfl_xor(mx, off, 16));
    float es = 0.f;
#pragma unroll
    for (int j = 0; j < 8; ++j) es += __expf(v[j] - mx);
#pragma unroll
    for (int off = 1; off < 16; off <<= 1) es += __shfl_xor(es, off, 16);
    float lse = mx + __logf(es);
    if (gn < NN){
      float4 o0 = make_float4(v[0] - lse, v[1] - lse, v[2] - lse, v[3] - lse);
      float4 o1v = make_float4(v[4] - lse, v[5] - lse, v[6] - lse, v[7] - lse);
      *(float4*)(o2 + (size_t)gn * 128 + tx * 4) = o0;
      *(float4*)(o2 + (size_t)gn * 128 + tx * 4 + 64) = o1v;
    }
  }
}

// ---- GCN aggregate of o2 with dinv weights ----
__global__ __launch_bounds__(256) void k_gcn_agg(
    const int* __restrict__ csr, const int* __restrict__ row_start,
    const float* __restrict__ dinv, const float* __restrict__ o2,
    float* __restrict__ aggD)
{
  int wid = (blockIdx.x * 256 + threadIdx.x) >> 6;
  int lane = threadIdx.x & 63;
  int half = lane >> 5, l32 = lane & 31;
  int d = wid * 2 + half;
  if (d >= NN) return;
  int beg = row_start[d], end = row_start[d + 1];
  float ax = 0.f, ay = 0.f, az = 0.f, aw = 0.f;
  float bx = 0.f, by = 0.f, bz = 0.f, bw = 0.f;
  int i = beg;
  for (; i + 1 < end; i += 2){
    int s0 = csr[i], s1 = csr[i + 1];
    float d0 = dinv[s0], d1 = dinv[s1];
    float4 v0 = *(const float4*)(o2 + (size_t)s0 * 128 + l32 * 4);
    float4 v1 = *(const float4*)(o2 + (size_t)s1 * 128 + l32 * 4);
    ax = fmaf(v0.x, d0, ax); ay = fmaf(v0.y, d0, ay); az = fmaf(v0.z, d0, az); aw = fmaf(v0.w, d0, aw);
    bx = fmaf(v1.x, d1, bx); by = fmaf(v1.y, d1, by); bz = fmaf(v1.z, d1, bz); bw = fmaf(v1.w, d1, bw);
  }
  if (i < end){
    int s0 = csr[i];
    float d0 = dinv[s0];
    float4 v0 = *(const float4*)(o2 + (size_t)s0 * 128 + l32 * 4);
    ax = fmaf(v0.x, d0, ax); ay = fmaf(v0.y, d0, ay); az = fmaf(v0.z, d0, az); aw = fmaf(v0.w, d0, aw);
  }
  float dd = dinv[d];
  float4 ov = make_float4((ax + bx) * dd, (ay + by) * dd, (az + bz) * dd, (aw + bw) * dd);
  *(float4*)(aggD + (size_t)d * 128 + l32 * 4) = ov;
}

// ---- final fused: out = relu(aggD @ Wg + bg) @ Wl + bl, natural layouts ----
__global__ __launch_bounds__(256) void k_final(const float* __restrict__ aggD,
    const float* __restrict__ Wg, const float* __restrict__ bg,
    const float* __restrict__ Wl, const float* __restrict__ bl,
    float* __restrict__ out)
{
  __shared__ float Ta[64][132];   // [node][k] natural; phase2: relu(T+bg)
  __shared__ float Ws[32][128];   // [k][out] natural, per 32-k chunk
  int t = threadIdx.x, tx = t & 15, ty = t >> 4;
  int n0 = blockIdx.x * 64;
#pragma unroll
  for (int p = 0; p < 8; ++p){
    int f = t + p * 256;           // 2048 float4 = 64 nodes x 32
    int node = f >> 5, cq = f & 31;
    float4 v = make_float4(0.f, 0.f, 0.f, 0.f);
    if (n0 + node < NN) v = *(const float4*)(aggD + (size_t)(n0 + node) * 128 + cq * 4);
    *(float4*)&Ta[node][cq * 4] = v;
  }
  float accv[4][8];
  const float* Wcur = Wg;
  for (int ph = 0; ph < 2; ++ph){
#pragma unroll
    for (int i = 0; i < 4; ++i)
#pragma unroll
      for (int j = 0; j < 8; ++j) accv[i][j] = 0.f;
    for (int kt = 0; kt < 128; kt += 32){
      __syncthreads();
#pragma unroll
      for (int p = 0; p < 4; ++p){
        int f = t + p * 256;       // 1024 float4 = 32 k x 32 cq
        int k = f >> 5, cq = f & 31;
        *(float4*)&Ws[k][cq * 4] = *(const float4*)(Wcur + (size_t)(kt + k) * 128 + cq * 4);
      }
      __syncthreads();
#pragma unroll 4
      for (int k = 0; k < 32; ++k){
        float a0 = Ta[ty * 4 + 0][kt + k];
        float a1 = Ta[ty * 4 + 1][kt + k];
        float a2 = Ta[ty * 4 + 2][kt + k];
        float a3 = Ta[ty * 4 + 3][kt + k];
        float4 c0 = *(const float4*)&Ws[k][tx * 4];
        float4 c1 = *(const float4*)&Ws[k][tx * 4 + 64];
        float bv[8] = {c0.x, c0.y, c0.z, c0.w, c1.x, c1.y, c1.z, c1.w};
#pragma unroll
        for (int j = 0; j < 8; ++j){
          accv[0][j] = fmaf(a0, bv[j], accv[0][j]);
          accv[1][j] = fmaf(a1, bv[j], accv[1][j]);
          accv[2][j] = fmaf(a2, bv[j], accv[2][j]);
          accv[3][j] = fmaf(a3, bv[j], accv[3][j]);
        }
      }
    }
    if (ph == 0){
      __syncthreads();
      // T = relu(acc + bg) back into Ta (natural writes: contiguous across tx)
#pragma unroll
      for (int i = 0; i < 4; ++i){
        int nloc = ty * 4 + i;
        float4 w0, w1;
        w0.x = fmaxf(accv[i][0] + bg[tx * 4 + 0], 0.f);
        w0.y = fmaxf(accv[i][1] + bg[tx * 4 + 1], 0.f);
        w0.z = fmaxf(accv[i][2] + bg[tx * 4 + 2], 0.f);
        w0.w = fmaxf(accv[i][3] + bg[tx * 4 + 3], 0.f);
        w1.x = fmaxf(accv[i][4] + bg[64 + tx * 4 + 0], 0.f);
        w1.y = fmaxf(accv[i][5] + bg[64 + tx * 4 + 1], 0.f);
        w1.z = fmaxf(accv[i][6] + bg[64 + tx * 4 + 2], 0.f);
        w1.w = fmaxf(accv[i][7] + bg[64 + tx * 4 + 3], 0.f);
        *(float4*)&Ta[nloc][tx * 4] = w0;
        *(float4*)&Ta[nloc][tx * 4 + 64] = w1;
      }
      Wcur = Wl;
    }
  }
#pragma unroll
  for (int i = 0; i < 4; ++i){
    int gn = n0 + ty * 4 + i;
    if (gn < NN){
      float4 o0, o1v;
      o0.x = accv[i][0] + bl[tx * 4 + 0];
      o0.y = accv[i][1] + bl[tx * 4 + 1];
      o0.z = accv[i][2] + bl[tx * 4 + 2];
      o0.w = accv[i][3] + bl[tx * 4 + 3];
      o1v.x = accv[i][4] + bl[64 + tx * 4 + 0];
      o1v.y = accv[i][5] + bl[64 + tx * 4 + 1];
      o1v.z = accv[i][6] + bl[64 + tx * 4 + 2];
      o1v.w = accv[i][7] + bl[64 + tx * 4 + 3];
      *(float4*)(out + (size_t)gn * 128 + tx * 4) = o0;
      *(float4*)(out + (size_t)gn * 128 + tx * 4 + 64) = o1v;
    }
  }
}

extern "C" void kernel_launch(void* const* d_in, const int* in_sizes, int n_in,
                              void* d_out, int out_size, void* d_ws, size_t ws_size,
                              hipStream_t stream)
{
  const float* x   = (const float*)d_in[0];
  const int*   ei  = (const int*)d_in[1];
  const float* W1  = (const float*)d_in[2];
  const float* as1 = (const float*)d_in[3];
  const float* ad1 = (const float*)d_in[4];
  const float* b1  = (const float*)d_in[5];
  const float* W2  = (const float*)d_in[6];
  const float* as2 = (const float*)d_in[7];
  const float* ad2 = (const float*)d_in[8];
  const float* b2  = (const float*)d_in[9];
  const float* Wg  = (const float*)d_in[10];
  const float* bg  = (const float*)d_in[11];
  const float* Wl  = (const float*)d_in[12];
  const float* bl  = (const float*)d_in[13];
  float* out = (float*)d_out;

  float* ws = (float*)d_ws;
  const size_t n = NN;
  float* h1   = ws;                 // 48N
  float* o1   = ws + 48 * n;        // 48N
  float* agg2 = ws + 96 * n;        // 48N
  float* o2   = ws + 144 * n;       // 128N
  float* aggD = ws + 272 * n;       // 128N
  float* es1  = ws + 400 * n;       // 3N
  float* ed1  = ws + 403 * n;       // 3N
  float* es2  = ws + 406 * n;       // N
  float* ed2  = ws + 407 * n;       // N
  float* dinv = ws + 408 * n;       // N
  float* w2as = ws + 409 * n;       // 64
  float* w2ad = ws + 409 * n + 64;  // 64
  int* ints   = (int*)(ws + 410 * n);
  int* deg_i     = ints;            // N (zeroed)
  int* cur       = ints + n;        // N (zeroed)
  int* row_start = ints + 2 * n;    // N+1
  int* csr       = ints + 3 * n + 1;// ET
  int* bsum      = ints + 3 * n + 1 + ET;      // NB
  int* boff      = ints + 3 * n + 1 + ET + NB; // NB

  hipMemsetAsync(deg_i, 0, 2 * n * sizeof(int), stream);

  const int egrid = (ET + 255) / 256;
  const int wgrid = (NN * 64) / 256;        // one wave per node
  const int hgrid = (NN / 2 * 64) / 256;    // two nodes per wave
  const int ggrid = (NN + 63) / 64;
  k_hist<<<egrid, 256, 0, stream>>>(ei, deg_i);
  k_scan_part<<<NB, 256, 0, stream>>>(deg_i, bsum);
  k_scan_top<<<1, 256, 0, stream>>>(bsum, boff);
  k_scan_fin<<<NB, 256, 0, stream>>>(deg_i, boff, row_start, dinv);
  k_fill<<<egrid, 256, 0, stream>>>(ei, row_start, cur, csr);
  k_w2<<<1, 64, 0, stream>>>(W2, as2, ad2, w2as, w2ad);
  k_gat1_gemm<<<ggrid, 256, 0, stream>>>(x, W1, as1, ad1, h1, es1, ed1);
  k_gat1_agg<<<wgrid, 256, 0, stream>>>(csr, row_start, es1, ed1, h1, b1, w2as, w2ad, o1, es2, ed2);
  k_gat2_agg<<<wgrid, 256, 0, stream>>>(csr, row_start, es2, ed2, o1, agg2);
  k_gat2_post<<<ggrid, 256, 0, stream>>>(agg2, W2, b2, o2);
  k_gcn_agg<<<hgrid, 256, 0, stream>>>(csr, row_start, dinv, o2, aggD);
  k_final<<<ggrid, 256, 0, stream>>>(aggD, Wg, bg, Wl, bl, out);
}